// Round 6
// baseline (271.493 us; speedup 1.0000x reference)
//
#include <hip/hip_runtime.h>
#include <hip/hip_bf16.h>
#include <math.h>

// Problem constants (fixed by the reference's weight shapes):
#define DM     256   // d_model
#define NHEAD  8
#define HDIM   32
#define QPAD   112   // padded query rows per (b,h): 7 waves x 16 rows
#define NCHUNK 8     // L-chunks per (b,h) for flash parallelism
#define BM     64    // kv_gemm M-tile (tokens)
#define BN     256   // kv_gemm N-tile (output cols): ntile 0 = K, 1 = V
#define BK     32    // kv_gemm K-step
#define ALD    264   // As row stride in shorts (256 + 8 pad)
#define QR     4     // q_proj rows per block
#define CQ     4     // combine queries per block

typedef __attribute__((ext_vector_type(8))) short bf16x8;  // 8 bf16 (4 VGPRs)
typedef __attribute__((ext_vector_type(4))) short bf16x4;  // 8B packed store
typedef __attribute__((ext_vector_type(4))) float f32x4;   // 4 fp32 acc

__device__ __forceinline__ short f2bf(float f) {
  union { float f; unsigned u; } x; x.f = f;
  unsigned u = (x.u + 0x7fffu + ((x.u >> 16) & 1u)) >> 16;
  return (short)u;
}
__device__ __forceinline__ float bf2f(short s) {
  union { unsigned u; float f; } x; x.u = ((unsigned)(unsigned short)s) << 16;
  return x.f;
}
__device__ __forceinline__ bf16x8 bzero8() {
  bf16x8 v;
#pragma unroll
  for (int j = 0; j < 8; j++) v[j] = (short)0;
  return v;
}
__device__ __forceinline__ bf16x8 cvt8(const float* p) {
  float4 x0 = *(const float4*)p, x1 = *(const float4*)(p + 4);
  bf16x8 v;
  v[0] = f2bf(x0.x); v[1] = f2bf(x0.y); v[2] = f2bf(x0.z); v[3] = f2bf(x0.w);
  v[4] = f2bf(x1.x); v[5] = f2bf(x1.y); v[6] = f2bf(x1.z); v[7] = f2bf(x1.w);
  return v;
}

// ---------------------------------------------------------------------------
// Kernel A (fused): q_proj blocks [0, nqb) + kv_gemm blocks [nqb, nqb+2048).
// - q_proj path: q = (query @ Wq^T + bq) * scale -> Qw bf16, QR rows/block.
// - kv path: best measured config (70-72 us): stage ALL of A (64x256 bf16 =
//   33.8 KB) into LDS once, then a barrier-free K-loop; B fragments read
//   straight from the L2-resident fp32 weights (Wk/Wv) and converted to bf16
//   in-register (kills the separate wconv dispatch). K/V-paired grid: the K
//   and V blocks of one mtile share kvbid%8 (same XCD) and are 8 IDs apart
//   -> src re-read is an L2 hit (FETCH ~34 MB).
//   K tiles use SWAPPED mfma operands (C^T); V tiles normal orientation.
// ---------------------------------------------------------------------------
__global__ __launch_bounds__(256) void kvq_kernel(
    const float* __restrict__ src, const float* __restrict__ query,
    const float* __restrict__ Wq, const float* __restrict__ bq,
    const float* __restrict__ Wk, const float* __restrict__ bk,
    const float* __restrict__ Wv, const float* __restrict__ bv,
    const int* __restrict__ offs, short* __restrict__ Qw,
    short* __restrict__ Kw, short* __restrict__ Vw, int T, int Bn, int NQ,
    int Mtiles, int nqb) {
  __shared__ __align__(16) short As[BM * ALD];   // kv path (33.8 KB)
  __shared__ __align__(16) float ql[QR * DM];    // q_proj path (4 KB)
  int tid = threadIdx.x;

  if (blockIdx.x < (unsigned)nqb) {
    // ---------------- q_proj path ----------------
    int b  = blockIdx.x / (QPAD / QR);
    int r0 = (blockIdx.x % (QPAD / QR)) * QR;
    for (int i = tid; i < QR * DM; i += 256) {
      int r = r0 + (i >> 8);
      ql[i] = (r < NQ) ? query[((size_t)b * NQ + r) * DM + (i & 255)] : 0.f;
    }
    __syncthreads();
    int d = tid;
    float bias = bq[d];
    float acc[QR];
#pragma unroll
    for (int qi = 0; qi < QR; qi++) acc[qi] = bias;
    const float* wrow = Wq + (size_t)d * DM;
    for (int k = 0; k < DM; k += 4) {
      float4 w = *(const float4*)(wrow + k);
#pragma unroll
      for (int qi = 0; qi < QR; qi++) {
        float4 x = *(const float4*)&ql[qi * DM + k];
        acc[qi] += x.x * w.x + x.y * w.y + x.z * w.z + x.w * w.w;
      }
    }
    const float scale = 0.17677669529663687f;  // 1/sqrt(32)
    int h = d >> 5, hd = d & 31;
#pragma unroll
    for (int qi = 0; qi < QR; qi++) {
      int r = r0 + qi;
      float v = (r < NQ) ? acc[qi] * scale : 0.f;
      Qw[(((size_t)b * NHEAD + h) * QPAD + r) * HDIM + hd] = f2bf(v);
    }
    return;
  }

  // ---------------- kv path ----------------
  int bid = blockIdx.x - nqb;
  int mtile = (bid >> 4) * 8 + (bid & 7);
  int ntile = (bid >> 3) & 1;
  if (mtile >= Mtiles) return;
  int t0 = mtile * BM;
  bool isK = (ntile == 0);
  const float* bias = isK ? bk : bv;
  const float* Wsel = isK ? Wk : Wv;

  int wave = tid >> 6, lane = tid & 63;
  int l15 = lane & 15, quad = lane >> 4;

  f32x4 acc[4][4];
#pragma unroll
  for (int i = 0; i < 4; i++)
#pragma unroll
    for (int j = 0; j < 4; j++) acc[i][j] = (f32x4){0.f, 0.f, 0.f, 0.f};

  // ---- prologue: stage all of A (fp32 -> bf16), one barrier total ----
  {
    int arow = tid >> 2, ac4 = tid & 3;
    int atok = t0 + arow;
    if (atok >= T) atok = T - 1;
    const float* arp = src + (size_t)atok * DM;
#pragma unroll
    for (int r = 0; r < 4; r++) {
      int c0 = r * 64 + ac4 * 16;
      const float* p = arp + c0;
      bf16x8 v0 = cvt8(p);
      bf16x8 v1 = cvt8(p + 8);
      *(bf16x8*)&As[arow * ALD + c0]     = v0;
      *(bf16x8*)&As[arow * ALD + c0 + 8] = v1;
    }
  }
  __syncthreads();

  // ---- barrier-free K-loop: B from fp32 weights (L2) + cvt, A from LDS ----
  const float* bptrf = Wsel + (size_t)(wave * 64 + l15) * DM + quad * 8;
#pragma unroll
  for (int kk = 0; kk < DM; kk += BK) {
    bf16x8 bf_[4];
#pragma unroll
    for (int nt = 0; nt < 4; nt++)
      bf_[nt] = cvt8(bptrf + (size_t)nt * 16 * DM + kk);
    bf16x8 af[4];
#pragma unroll
    for (int mt = 0; mt < 4; mt++)
      af[mt] = *(const bf16x8*)&As[(mt * 16 + l15) * ALD + kk + quad * 8];
    if (isK) {
#pragma unroll
      for (int mt = 0; mt < 4; mt++)
#pragma unroll
        for (int nt = 0; nt < 4; nt++)
          acc[mt][nt] = __builtin_amdgcn_mfma_f32_16x16x32_bf16(
              bf_[nt], af[mt], acc[mt][nt], 0, 0, 0);  // C^T
    } else {
#pragma unroll
      for (int mt = 0; mt < 4; mt++)
#pragma unroll
        for (int nt = 0; nt < 4; nt++)
          acc[mt][nt] = __builtin_amdgcn_mfma_f32_16x16x32_bf16(
              af[mt], bf_[nt], acc[mt][nt], 0, 0, 0);
    }
  }

  if (isK) {
    // C^T: lane l15 = token (within 16), reg r = hd offset quad*4+r.
    float bk4[4][4];
    int hK[4], hdK[4];
#pragma unroll
    for (int nt = 0; nt < 4; nt++) {
      int nbq = wave * 64 + nt * 16 + quad * 4;
      float4 b4 = *(const float4*)(bias + nbq);
      bk4[nt][0] = b4.x; bk4[nt][1] = b4.y; bk4[nt][2] = b4.z; bk4[nt][3] = b4.w;
      hK[nt] = nbq >> 5;
      hdK[nt] = nbq & 31;
    }
    int bcur = 0;
#pragma unroll
    for (int mt = 0; mt < 4; mt++) {
      int tok = t0 + mt * 16 + l15;
      if (tok >= T) continue;
      while (bcur + 1 < Bn && offs[bcur + 1] <= tok) bcur++;
      int off = offs[bcur], len = offs[bcur + 1] - off;
      int l = tok - off;
      size_t bb = (size_t)off * DM;
#pragma unroll
      for (int nt = 0; nt < 4; nt++) {
        bf16x4 p;
#pragma unroll
        for (int r = 0; r < 4; r++) p[r] = f2bf(acc[mt][nt][r] + bk4[nt][r]);
        *(bf16x4*)&Kw[bb + (size_t)hK[nt] * len * HDIM + (size_t)l * HDIM +
                      hdK[nt]] = p;
      }
    }
  } else {
    // Normal C: lane l15 = hd (within 16), reg r = token offset quad*4+r.
    float bV[4];
    int hV[4], hdV[4];
#pragma unroll
    for (int nt = 0; nt < 4; nt++) {
      int nb = wave * 64 + nt * 16 + l15;
      bV[nt] = bias[nb];
      hV[nt] = nb >> 5;
      hdV[nt] = nb & 31;
    }
    int bcur = 0;
#pragma unroll
    for (int mt = 0; mt < 4; mt++) {
      int tb = t0 + mt * 16 + quad * 4;
      if (tb >= T) continue;
      while (bcur + 1 < Bn && offs[bcur + 1] <= tb) bcur++;
      int off = offs[bcur], len = offs[bcur + 1] - off;
      size_t bb = (size_t)off * DM;
      bool span = (tb + 3 < offs[bcur + 1]) && (tb + 3 < T);
      if (span) {
        int l = tb - off;
#pragma unroll
        for (int nt = 0; nt < 4; nt++) {
          size_t idx =
              bb + (size_t)hV[nt] * len * HDIM + (size_t)hdV[nt] * len + l;
          bf16x4 p;
#pragma unroll
          for (int r = 0; r < 4; r++) p[r] = f2bf(acc[mt][nt][r] + bV[nt]);
          if ((idx & 3) == 0) {
            *(bf16x4*)&Vw[idx] = p;
          } else {
#pragma unroll
            for (int r = 0; r < 4; r++) Vw[idx + r] = p[r];
          }
        }
      } else {
        int bc2 = bcur;
#pragma unroll
        for (int r = 0; r < 4; r++) {
          int tok = tb + r;
          if (tok >= T) continue;
          while (bc2 + 1 < Bn && offs[bc2 + 1] <= tok) bc2++;
          int off2 = offs[bc2], len2 = offs[bc2 + 1] - off2;
          int l = tok - off2;
          size_t bb2 = (size_t)off2 * DM;
#pragma unroll
          for (int nt = 0; nt < 4; nt++)
            Vw[bb2 + (size_t)hV[nt] * len2 * HDIM + (size_t)hdV[nt] * len2 +
               l] = f2bf(acc[mt][nt][r] + bV[nt]);
        }
      }
    }
  }
}

// ---------------------------------------------------------------------------
// Kernel 3: flash attention per (b, h, chunk). 7 waves x 16 query rows.
// Round-6: 64-key iterations (4 QK tiles/step). The per-r-group shfl cascade
// (4 max + 4 sum) is amortized over 64 keys instead of 32 -> shfl count
// halves; the serial m-chain is 9 iterations instead of 17.
// Writes unnormalized O (QPAD x 32, bf16) + per-row (m, l) fp32.
// ---------------------------------------------------------------------------
__global__ __launch_bounds__(448) void attn_kernel(
    const short* __restrict__ Qw, const short* __restrict__ Kw,
    const short* __restrict__ Vw, const int* __restrict__ offs,
    short* __restrict__ Ops, float* __restrict__ Ml, int Bn) {
  int c  = blockIdx.x % NCHUNK;
  int bh = blockIdx.x / NCHUNK;
  int h = bh % NHEAD, b = bh / NHEAD;
  int wave = threadIdx.x >> 6, lane = threadIdx.x & 63;
  int l15 = lane & 15, quad = lane >> 4;

  int off = offs[b], len = offs[b + 1] - off;
  int cl = ((len + NCHUNK * 32 - 1) / (NCHUNK * 32)) * 32;
  int kstart = c * cl;
  int kend   = min(kstart + cl, len);

  const short* Kh = Kw + (size_t)off * DM + (size_t)h * len * HDIM;
  const short* Vh = Vw + (size_t)off * DM + (size_t)h * len * HDIM;

  int row16 = wave * 16 + l15;
  bf16x8 aq = *(const bf16x8*)(
      Qw + (((size_t)b * NHEAD + h) * QPAD + row16) * HDIM + quad * 8);

  f32x4 o[2];
#pragma unroll
  for (int j = 0; j < 2; j++) o[j] = (f32x4){0.f, 0.f, 0.f, 0.f};
  float mrun[4], lrun[4];
#pragma unroll
  for (int r = 0; r < 4; r++) { mrun[r] = -1e30f; lrun[r] = 0.f; }

  __shared__ __align__(16) short plds[7][16][72];  // wave-private P transpose

  for (int kb = kstart; kb < kend; kb += 64) {
    bool valid[4];
    bf16x8 bk_[4];
#pragma unroll
    for (int nt = 0; nt < 4; nt++) {
      int key = kb + nt * 16 + l15;
      valid[nt] = key < kend;
      bk_[nt] = valid[nt]
                    ? *(const bf16x8*)(Kh + (size_t)key * HDIM + quad * 8)
                    : bzero8();
    }
    f32x4 zero = {0.f, 0.f, 0.f, 0.f};
    f32x4 s[4];
#pragma unroll
    for (int nt = 0; nt < 4; nt++)
      s[nt] = __builtin_amdgcn_mfma_f32_16x16x32_bf16(aq, bk_[nt], zero, 0, 0, 0);
#pragma unroll
    for (int r = 0; r < 4; r++) {
      float v0 = valid[0] ? s[0][r] : -1e30f;
      float v1 = valid[1] ? s[1][r] : -1e30f;
      float v2 = valid[2] ? s[2][r] : -1e30f;
      float v3 = valid[3] ? s[3][r] : -1e30f;
      float t = fmaxf(fmaxf(v0, v1), fmaxf(v2, v3));
      t = fmaxf(t, __shfl_xor(t, 1, 16));
      t = fmaxf(t, __shfl_xor(t, 2, 16));
      t = fmaxf(t, __shfl_xor(t, 4, 16));
      t = fmaxf(t, __shfl_xor(t, 8, 16));
      float mn = fmaxf(mrun[r], t);
      float al = __expf(mrun[r] - mn);
      float p0 = valid[0] ? __expf(v0 - mn) : 0.f;
      float p1 = valid[1] ? __expf(v1 - mn) : 0.f;
      float p2 = valid[2] ? __expf(v2 - mn) : 0.f;
      float p3 = valid[3] ? __expf(v3 - mn) : 0.f;
      float rs = (p0 + p1) + (p2 + p3);
      rs += __shfl_xor(rs, 1, 16);
      rs += __shfl_xor(rs, 2, 16);
      rs += __shfl_xor(rs, 4, 16);
      rs += __shfl_xor(rs, 8, 16);
      lrun[r] = al * lrun[r] + rs;
      mrun[r] = mn;
      o[0][r] *= al;
      o[1][r] *= al;
      plds[wave][quad * 4 + r][l15]      = f2bf(p0);
      plds[wave][quad * 4 + r][16 + l15] = f2bf(p1);
      plds[wave][quad * 4 + r][32 + l15] = f2bf(p2);
      plds[wave][quad * 4 + r][48 + l15] = f2bf(p3);
    }
    bf16x8 pa0 = *(const bf16x8*)&plds[wave][l15][quad * 8];
    bf16x8 pa1 = *(const bf16x8*)&plds[wave][l15][32 + quad * 8];
    bf16x8 bv_[2][2];
#pragma unroll
    for (int half = 0; half < 2; half++) {
#pragma unroll
      for (int ht = 0; ht < 2; ht++) {
        int hd = ht * 16 + l15;
        int k0 = kb + half * 32 + quad * 8;
        const short* p = Vh + (size_t)hd * len + k0;
        if (k0 + 7 < len) {
          bv_[half][ht] = *(const bf16x8*)p;
        } else {
          bf16x8 v;
#pragma unroll
          for (int j = 0; j < 8; j++) v[j] = (k0 + j < len) ? p[j] : (short)0;
          bv_[half][ht] = v;
        }
      }
    }
#pragma unroll
    for (int ht = 0; ht < 2; ht++) {
      o[ht] = __builtin_amdgcn_mfma_f32_16x16x32_bf16(pa0, bv_[0][ht], o[ht],
                                                      0, 0, 0);
      o[ht] = __builtin_amdgcn_mfma_f32_16x16x32_bf16(pa1, bv_[1][ht], o[ht],
                                                      0, 0, 0);
    }
  }

#pragma unroll
  for (int r = 0; r < 4; r++) {
    int row = wave * 16 + quad * 4 + r;
    size_t base = (((size_t)c * Bn + b) * NHEAD + h) * QPAD + row;
#pragma unroll
    for (int ht = 0; ht < 2; ht++)
      Ops[base * HDIM + ht * 16 + l15] = f2bf(o[ht][r]);
    if (l15 == 0) {
      Ml[base * 2]     = mrun[r];
      Ml[base * 2 + 1] = lrun[r];
    }
  }
}

// ---------------------------------------------------------------------------
// Kernel 4: chunk combine + out-projection + residual. CQ=4 queries/block,
// LDS-staged vectorized Ops/Ml loads.
// ---------------------------------------------------------------------------
__global__ __launch_bounds__(256) void combine_kernel(
    const short* __restrict__ Ops, const float* __restrict__ Ml,
    const float* __restrict__ query, const float* __restrict__ Wo,
    const float* __restrict__ bo, float* __restrict__ out, int Bn, int NQ) {
  int bpb = (NQ + CQ - 1) / CQ;
  int b  = blockIdx.x / bpb;
  int q0 = (blockIdx.x % bpb) * CQ;
  int tid = threadIdx.x;

  __shared__ __align__(16) short opsl[CQ][NCHUNK][DM];  // 16 KB
  __shared__ float mll[NCHUNK][NHEAD][CQ][2];           // 2 KB
  __shared__ __align__(16) float ctx[CQ * DM];          // 4 KB

  for (int t = tid; t < CQ * NCHUNK * (DM / 8); t += 256) {
    int q   = t / (NCHUNK * 32);
    int rem = t % (NCHUNK * 32);
    int c   = rem / 32;
    int v   = rem % 32;           // 8-elem chunk within 256 = h*32+hd0
    int h   = v >> 2;
    int hd0 = (v & 3) * 8;
    int qq = q0 + q;
    if (qq >= NQ) qq = NQ - 1;
    size_t base = (((size_t)c * Bn + b) * NHEAD + h) * QPAD + qq;
    *(bf16x8*)&opsl[q][c][v * 8] = *(const bf16x8*)&Ops[base * HDIM + hd0];
  }
  for (int t = tid; t < CQ * NCHUNK * NHEAD; t += 256) {
    int q   = t / (NCHUNK * NHEAD);
    int rem = t % (NCHUNK * NHEAD);
    int c   = rem / NHEAD;
    int h   = rem % NHEAD;
    int qq = q0 + q;
    if (qq >= NQ) qq = NQ - 1;
    size_t base = (((size_t)c * Bn + b) * NHEAD + h) * QPAD + qq;
    mll[c][h][q][0] = Ml[base * 2];
    mll[c][h][q][1] = Ml[base * 2 + 1];
  }
  __syncthreads();

  int d = tid, h = d >> 5;
#pragma unroll
  for (int qi = 0; qi < CQ; qi++) {
    float M = -1e30f;
#pragma unroll
    for (int c = 0; c < NCHUNK; c++) M = fmaxf(M, mll[c][h][qi][0]);
    float L = 0.f, acc = 0.f;
#pragma unroll
    for (int c = 0; c < NCHUNK; c++) {
      float w = __expf(mll[c][h][qi][0] - M);
      L += mll[c][h][qi][1] * w;
      acc += w * bf2f(opsl[qi][c][d]);
    }
    ctx[qi * DM + d] = (L > 0.f) ? acc / L : 0.f;
  }
  __syncthreads();

  const float* wrow = Wo + (size_t)d * DM;
  float acc[CQ];
  float bias = bo[d];
#pragma unroll
  for (int qi = 0; qi < CQ; qi++) acc[qi] = bias;
  for (int k = 0; k < DM; k += 4) {
    float4 w = *(const float4*)(wrow + k);
#pragma unroll
    for (int qi = 0; qi < CQ; qi++) {
      float4 x = *(const float4*)&ctx[qi * DM + k];
      acc[qi] += x.x * w.x + x.y * w.y + x.z * w.z + x.w * w.w;
    }
  }
#pragma unroll
  for (int qi = 0; qi < CQ; qi++) {
    int q = q0 + qi;
    if (q < NQ)
      out[((size_t)b * NQ + q) * DM + d] =
          acc[qi] + query[((size_t)b * NQ + q) * DM + d];
  }
}

// ---------------------------------------------------------------------------
extern "C" void kernel_launch(void* const* d_in, const int* in_sizes, int n_in,
                              void* d_out, int out_size, void* d_ws,
                              size_t ws_size, hipStream_t stream) {
  const float* src   = (const float*)d_in[0];
  const float* query = (const float*)d_in[1];
  const int*   offs  = (const int*)d_in[2];
  const float* Wq = (const float*)d_in[3];
  const float* bq = (const float*)d_in[4];
  const float* Wk = (const float*)d_in[5];
  const float* bk = (const float*)d_in[6];
  const float* Wv = (const float*)d_in[7];
  const float* bv = (const float*)d_in[8];
  const float* Wo = (const float*)d_in[9];
  const float* bo = (const float*)d_in[10];
  float* out = (float*)d_out;

  int T  = in_sizes[0] / DM;        // total tokens (65536)
  int Bn = in_sizes[2] - 1;         // batch size (16)
  int NQ = in_sizes[1] / (Bn * DM); // queries per sample (100)

  // Workspace layout (~77 MB):
  char* w = (char*)d_ws;
  size_t qsz = (size_t)Bn * NHEAD * QPAD * HDIM * 2;            // 0.92 MB
  size_t ksz = (size_t)T * DM * 2;                              // 33.5 MB
  size_t osz = (size_t)NCHUNK * Bn * NHEAD * QPAD * HDIM * 2;   // 7.3 MB (bf16)
  short* Qw  = (short*)w;
  short* Kw  = (short*)(w + qsz);
  short* Vw  = (short*)(w + qsz + ksz);
  short* Ops = (short*)(w + qsz + 2 * ksz);
  float* Mlp = (float*)(w + qsz + 2 * ksz + osz);

  int Mtiles = (T + BM - 1) / BM;
  int groups = (Mtiles + 7) / 8;
  int nqb = Bn * (QPAD / QR);       // q_proj blocks (448)

  kvq_kernel<<<nqb + groups * 16, 256, 0, stream>>>(
      src, query, Wq, bq, Wk, bk, Wv, bv, offs, Qw, Kw, Vw, T, Bn, NQ, Mtiles,
      nqb);
  attn_kernel<<<Bn * NHEAD * NCHUNK, 448, 0, stream>>>(Qw, Kw, Vw, offs, Ops,
                                                       Mlp, Bn);
  combine_kernel<<<Bn * ((NQ + CQ - 1) / CQ), 256, 0, stream>>>(
      Ops, Mlp, query, Wo, bo, out, Bn, NQ);
}

// Round 7
// 248.731 us; speedup vs baseline: 1.0915x; 1.0915x over previous
//
#include <hip/hip_runtime.h>
#include <hip/hip_bf16.h>
#include <math.h>

// Problem constants (fixed by the reference's weight shapes):
#define DM     256   // d_model
#define NHEAD  8
#define HDIM   32
#define QPAD   112   // padded query rows per (b,h): 7 waves x 16 rows
#define NCHUNK 8     // L-chunks per (b,h) for flash parallelism
#define BM     64    // kv_gemm M-tile (tokens)
#define BN     256   // kv_gemm N-tile (output cols): ntile 0 = K, 1 = V
#define BK     32    // kv_gemm K-step
#define ALD    264   // As row stride in shorts (256 + 8 pad)
#define QR     4     // q_proj rows per block
#define CQ     4     // combine queries per block

typedef __attribute__((ext_vector_type(8))) short bf16x8;  // 8 bf16 (4 VGPRs)
typedef __attribute__((ext_vector_type(4))) short bf16x4;  // 8B packed store
typedef __attribute__((ext_vector_type(4))) float f32x4;   // 4 fp32 acc

__device__ __forceinline__ short f2bf(float f) {
  union { float f; unsigned u; } x; x.f = f;
  unsigned u = (x.u + 0x7fffu + ((x.u >> 16) & 1u)) >> 16;
  return (short)u;
}
__device__ __forceinline__ float bf2f(short s) {
  union { unsigned u; float f; } x; x.u = ((unsigned)(unsigned short)s) << 16;
  return x.f;
}
__device__ __forceinline__ bf16x8 bzero8() {
  bf16x8 v;
#pragma unroll
  for (int j = 0; j < 8; j++) v[j] = (short)0;
  return v;
}
__device__ __forceinline__ bf16x8 cvt8(const float* p) {
  float4 x0 = *(const float4*)p, x1 = *(const float4*)(p + 4);
  bf16x8 v;
  v[0] = f2bf(x0.x); v[1] = f2bf(x0.y); v[2] = f2bf(x0.z); v[3] = f2bf(x0.w);
  v[4] = f2bf(x1.x); v[5] = f2bf(x1.y); v[6] = f2bf(x1.z); v[7] = f2bf(x1.w);
  return v;
}

// ---------------------------------------------------------------------------
// Kernel 0: weight convert.  Wkv[n][k] bf16; n<256 -> Wk row n, else Wv.
// Tiny (64 blocks, ~3 us) but keeps the kv K-loop's B-reads at 16B bf16 —
// round-6 showed in-loop fp32->bf16 conversion costs +45 us on the kv path.
// ---------------------------------------------------------------------------
__global__ __launch_bounds__(256) void wconv_kernel(
    const float* __restrict__ Wk, const float* __restrict__ Wv,
    short* __restrict__ Wkv) {
  int idx = blockIdx.x * 256 + threadIdx.x;
  int e0 = idx * 8;
  const float* p = (e0 < DM * DM) ? (Wk + e0) : (Wv + (e0 - DM * DM));
  *(bf16x8*)(Wkv + e0) = cvt8(p);
}

// ---------------------------------------------------------------------------
// Kernel A (fused): kv_gemm blocks [0, kvb) + q_proj blocks [kvb, kvb+nqb).
// kv path = best measured config (70-72 us): stage ALL of A (64x256 bf16 =
// 33.8 KB) into LDS once, then a barrier-free K-loop; B fragments read from
// the L2-resident bf16 Wkv straight into MFMA layout. K/V-paired grid: the
// K and V blocks of one mtile share bid%8 (same XCD) and are 8 IDs apart ->
// src re-read is an L2 hit (FETCH ~34 MB).
// K tiles use SWAPPED mfma operands (C^T); V tiles normal orientation.
// q_proj blocks trail the grid as latency-bound filler (hidden under kv).
// ---------------------------------------------------------------------------
__global__ __launch_bounds__(256) void kvq_kernel(
    const float* __restrict__ src, const float* __restrict__ query,
    const float* __restrict__ Wq, const float* __restrict__ bq,
    const short* __restrict__ Wkv, const float* __restrict__ bk,
    const float* __restrict__ bv, const int* __restrict__ offs,
    short* __restrict__ Qw, short* __restrict__ Kw, short* __restrict__ Vw,
    int T, int Bn, int NQ, int Mtiles, int kvb) {
  __shared__ __align__(16) short As[BM * ALD];   // kv path (33.8 KB)
  __shared__ __align__(16) float ql[QR * DM];    // q_proj path (4 KB)
  int tid = threadIdx.x;

  if (blockIdx.x >= (unsigned)kvb) {
    // ---------------- q_proj path ----------------
    int qbid = blockIdx.x - kvb;
    int b  = qbid / (QPAD / QR);
    int r0 = (qbid % (QPAD / QR)) * QR;
    for (int i = tid; i < QR * DM; i += 256) {
      int r = r0 + (i >> 8);
      ql[i] = (r < NQ) ? query[((size_t)b * NQ + r) * DM + (i & 255)] : 0.f;
    }
    __syncthreads();
    int d = tid;
    float bias = bq[d];
    float acc[QR];
#pragma unroll
    for (int qi = 0; qi < QR; qi++) acc[qi] = bias;
    const float* wrow = Wq + (size_t)d * DM;
    for (int k = 0; k < DM; k += 4) {
      float4 w = *(const float4*)(wrow + k);
#pragma unroll
      for (int qi = 0; qi < QR; qi++) {
        float4 x = *(const float4*)&ql[qi * DM + k];
        acc[qi] += x.x * w.x + x.y * w.y + x.z * w.z + x.w * w.w;
      }
    }
    const float scale = 0.17677669529663687f;  // 1/sqrt(32)
    int h = d >> 5, hd = d & 31;
#pragma unroll
    for (int qi = 0; qi < QR; qi++) {
      int r = r0 + qi;
      float v = (r < NQ) ? acc[qi] * scale : 0.f;
      Qw[(((size_t)b * NHEAD + h) * QPAD + r) * HDIM + hd] = f2bf(v);
    }
    return;
  }

  // ---------------- kv path ----------------
  int bid = blockIdx.x;
  int mtile = (bid >> 4) * 8 + (bid & 7);
  int ntile = (bid >> 3) & 1;
  if (mtile >= Mtiles) return;
  int t0 = mtile * BM;
  int n0 = ntile * BN;           // 0 => K cols, 256 => V cols
  bool isK = (ntile == 0);
  const float* bias = isK ? bk : bv;

  int wave = tid >> 6, lane = tid & 63;
  int l15 = lane & 15, quad = lane >> 4;

  f32x4 acc[4][4];
#pragma unroll
  for (int i = 0; i < 4; i++)
#pragma unroll
    for (int j = 0; j < 4; j++) acc[i][j] = (f32x4){0.f, 0.f, 0.f, 0.f};

  // ---- prologue: stage all of A (fp32 -> bf16), one barrier total ----
  {
    int arow = tid >> 2, ac4 = tid & 3;
    int atok = t0 + arow;
    if (atok >= T) atok = T - 1;
    const float* arp = src + (size_t)atok * DM;
#pragma unroll
    for (int r = 0; r < 4; r++) {
      int c0 = r * 64 + ac4 * 16;
      const float* p = arp + c0;
      bf16x8 v0 = cvt8(p);
      bf16x8 v1 = cvt8(p + 8);
      *(bf16x8*)&As[arow * ALD + c0]     = v0;
      *(bf16x8*)&As[arow * ALD + c0 + 8] = v1;
    }
  }
  __syncthreads();

  // ---- barrier-free K-loop: B from bf16 Wkv (L2), A from LDS ----
  const short* bptr = Wkv + (size_t)(n0 + wave * 64 + l15) * DM + quad * 8;
#pragma unroll
  for (int kk = 0; kk < DM; kk += BK) {
    bf16x8 bf_[4];
#pragma unroll
    for (int nt = 0; nt < 4; nt++)
      bf_[nt] = *(const bf16x8*)(bptr + (size_t)nt * 16 * DM + kk);
    bf16x8 af[4];
#pragma unroll
    for (int mt = 0; mt < 4; mt++)
      af[mt] = *(const bf16x8*)&As[(mt * 16 + l15) * ALD + kk + quad * 8];
    if (isK) {
#pragma unroll
      for (int mt = 0; mt < 4; mt++)
#pragma unroll
        for (int nt = 0; nt < 4; nt++)
          acc[mt][nt] = __builtin_amdgcn_mfma_f32_16x16x32_bf16(
              bf_[nt], af[mt], acc[mt][nt], 0, 0, 0);  // C^T
    } else {
#pragma unroll
      for (int mt = 0; mt < 4; mt++)
#pragma unroll
        for (int nt = 0; nt < 4; nt++)
          acc[mt][nt] = __builtin_amdgcn_mfma_f32_16x16x32_bf16(
              af[mt], bf_[nt], acc[mt][nt], 0, 0, 0);
    }
  }

  if (isK) {
    // C^T: lane l15 = token (within 16), reg r = hd offset quad*4+r.
    float bk4[4][4];
    int hK[4], hdK[4];
#pragma unroll
    for (int nt = 0; nt < 4; nt++) {
      int nbq = wave * 64 + nt * 16 + quad * 4;
      float4 b4 = *(const float4*)(bias + nbq);
      bk4[nt][0] = b4.x; bk4[nt][1] = b4.y; bk4[nt][2] = b4.z; bk4[nt][3] = b4.w;
      hK[nt] = nbq >> 5;
      hdK[nt] = nbq & 31;
    }
    int bcur = 0;
#pragma unroll
    for (int mt = 0; mt < 4; mt++) {
      int tok = t0 + mt * 16 + l15;
      if (tok >= T) continue;
      while (bcur + 1 < Bn && offs[bcur + 1] <= tok) bcur++;
      int off = offs[bcur], len = offs[bcur + 1] - off;
      int l = tok - off;
      size_t bb = (size_t)off * DM;
#pragma unroll
      for (int nt = 0; nt < 4; nt++) {
        bf16x4 p;
#pragma unroll
        for (int r = 0; r < 4; r++) p[r] = f2bf(acc[mt][nt][r] + bk4[nt][r]);
        *(bf16x4*)&Kw[bb + (size_t)hK[nt] * len * HDIM + (size_t)l * HDIM +
                      hdK[nt]] = p;
      }
    }
  } else {
    // Normal C: lane l15 = hd (within 16), reg r = token offset quad*4+r.
    float bV[4];
    int hV[4], hdV[4];
#pragma unroll
    for (int nt = 0; nt < 4; nt++) {
      int nb = wave * 64 + nt * 16 + l15;
      bV[nt] = bias[nb];
      hV[nt] = nb >> 5;
      hdV[nt] = nb & 31;
    }
    int bcur = 0;
#pragma unroll
    for (int mt = 0; mt < 4; mt++) {
      int tb = t0 + mt * 16 + quad * 4;
      if (tb >= T) continue;
      while (bcur + 1 < Bn && offs[bcur + 1] <= tb) bcur++;
      int off = offs[bcur], len = offs[bcur + 1] - off;
      size_t bb = (size_t)off * DM;
      bool span = (tb + 3 < offs[bcur + 1]) && (tb + 3 < T);
      if (span) {
        int l = tb - off;
#pragma unroll
        for (int nt = 0; nt < 4; nt++) {
          size_t idx =
              bb + (size_t)hV[nt] * len * HDIM + (size_t)hdV[nt] * len + l;
          bf16x4 p;
#pragma unroll
          for (int r = 0; r < 4; r++) p[r] = f2bf(acc[mt][nt][r] + bV[nt]);
          if ((idx & 3) == 0) {
            *(bf16x4*)&Vw[idx] = p;
          } else {
#pragma unroll
            for (int r = 0; r < 4; r++) Vw[idx + r] = p[r];
          }
        }
      } else {
        int bc2 = bcur;
#pragma unroll
        for (int r = 0; r < 4; r++) {
          int tok = tb + r;
          if (tok >= T) continue;
          while (bc2 + 1 < Bn && offs[bc2 + 1] <= tok) bc2++;
          int off2 = offs[bc2], len2 = offs[bc2 + 1] - off2;
          int l = tok - off2;
          size_t bb2 = (size_t)off2 * DM;
#pragma unroll
          for (int nt = 0; nt < 4; nt++)
            Vw[bb2 + (size_t)hV[nt] * len2 * HDIM + (size_t)hdV[nt] * len2 +
               l] = f2bf(acc[mt][nt][r] + bV[nt]);
        }
      }
    }
  }
}

// ---------------------------------------------------------------------------
// Kernel 3: flash attention per (b, h, chunk). 7 waves x 16 query rows.
// 64-key iterations (4 QK tiles/step): shfl cascade amortized over 64 keys,
// serial m-chain 9 iterations instead of 17 (measured ~30 us total gain).
// Writes unnormalized O (QPAD x 32, bf16) + per-row (m, l) fp32.
// ---------------------------------------------------------------------------
__global__ __launch_bounds__(448) void attn_kernel(
    const short* __restrict__ Qw, const short* __restrict__ Kw,
    const short* __restrict__ Vw, const int* __restrict__ offs,
    short* __restrict__ Ops, float* __restrict__ Ml, int Bn) {
  int c  = blockIdx.x % NCHUNK;
  int bh = blockIdx.x / NCHUNK;
  int h = bh % NHEAD, b = bh / NHEAD;
  int wave = threadIdx.x >> 6, lane = threadIdx.x & 63;
  int l15 = lane & 15, quad = lane >> 4;

  int off = offs[b], len = offs[b + 1] - off;
  int cl = ((len + NCHUNK * 32 - 1) / (NCHUNK * 32)) * 32;
  int kstart = c * cl;
  int kend   = min(kstart + cl, len);

  const short* Kh = Kw + (size_t)off * DM + (size_t)h * len * HDIM;
  const short* Vh = Vw + (size_t)off * DM + (size_t)h * len * HDIM;

  int row16 = wave * 16 + l15;
  bf16x8 aq = *(const bf16x8*)(
      Qw + (((size_t)b * NHEAD + h) * QPAD + row16) * HDIM + quad * 8);

  f32x4 o[2];
#pragma unroll
  for (int j = 0; j < 2; j++) o[j] = (f32x4){0.f, 0.f, 0.f, 0.f};
  float mrun[4], lrun[4];
#pragma unroll
  for (int r = 0; r < 4; r++) { mrun[r] = -1e30f; lrun[r] = 0.f; }

  __shared__ __align__(16) short plds[7][16][72];  // wave-private P transpose

  for (int kb = kstart; kb < kend; kb += 64) {
    bool valid[4];
    bf16x8 bk_[4];
#pragma unroll
    for (int nt = 0; nt < 4; nt++) {
      int key = kb + nt * 16 + l15;
      valid[nt] = key < kend;
      bk_[nt] = valid[nt]
                    ? *(const bf16x8*)(Kh + (size_t)key * HDIM + quad * 8)
                    : bzero8();
    }
    f32x4 zero = {0.f, 0.f, 0.f, 0.f};
    f32x4 s[4];
#pragma unroll
    for (int nt = 0; nt < 4; nt++)
      s[nt] = __builtin_amdgcn_mfma_f32_16x16x32_bf16(aq, bk_[nt], zero, 0, 0, 0);
#pragma unroll
    for (int r = 0; r < 4; r++) {
      float v0 = valid[0] ? s[0][r] : -1e30f;
      float v1 = valid[1] ? s[1][r] : -1e30f;
      float v2 = valid[2] ? s[2][r] : -1e30f;
      float v3 = valid[3] ? s[3][r] : -1e30f;
      float t = fmaxf(fmaxf(v0, v1), fmaxf(v2, v3));
      t = fmaxf(t, __shfl_xor(t, 1, 16));
      t = fmaxf(t, __shfl_xor(t, 2, 16));
      t = fmaxf(t, __shfl_xor(t, 4, 16));
      t = fmaxf(t, __shfl_xor(t, 8, 16));
      float mn = fmaxf(mrun[r], t);
      float al = __expf(mrun[r] - mn);
      float p0 = valid[0] ? __expf(v0 - mn) : 0.f;
      float p1 = valid[1] ? __expf(v1 - mn) : 0.f;
      float p2 = valid[2] ? __expf(v2 - mn) : 0.f;
      float p3 = valid[3] ? __expf(v3 - mn) : 0.f;
      float rs = (p0 + p1) + (p2 + p3);
      rs += __shfl_xor(rs, 1, 16);
      rs += __shfl_xor(rs, 2, 16);
      rs += __shfl_xor(rs, 4, 16);
      rs += __shfl_xor(rs, 8, 16);
      lrun[r] = al * lrun[r] + rs;
      mrun[r] = mn;
      o[0][r] *= al;
      o[1][r] *= al;
      plds[wave][quad * 4 + r][l15]      = f2bf(p0);
      plds[wave][quad * 4 + r][16 + l15] = f2bf(p1);
      plds[wave][quad * 4 + r][32 + l15] = f2bf(p2);
      plds[wave][quad * 4 + r][48 + l15] = f2bf(p3);
    }
    bf16x8 pa0 = *(const bf16x8*)&plds[wave][l15][quad * 8];
    bf16x8 pa1 = *(const bf16x8*)&plds[wave][l15][32 + quad * 8];
    bf16x8 bv_[2][2];
#pragma unroll
    for (int half = 0; half < 2; half++) {
#pragma unroll
      for (int ht = 0; ht < 2; ht++) {
        int hd = ht * 16 + l15;
        int k0 = kb + half * 32 + quad * 8;
        const short* p = Vh + (size_t)hd * len + k0;
        if (k0 + 7 < len) {
          bv_[half][ht] = *(const bf16x8*)p;
        } else {
          bf16x8 v;
#pragma unroll
          for (int j = 0; j < 8; j++) v[j] = (k0 + j < len) ? p[j] : (short)0;
          bv_[half][ht] = v;
        }
      }
    }
#pragma unroll
    for (int ht = 0; ht < 2; ht++) {
      o[ht] = __builtin_amdgcn_mfma_f32_16x16x32_bf16(pa0, bv_[0][ht], o[ht],
                                                      0, 0, 0);
      o[ht] = __builtin_amdgcn_mfma_f32_16x16x32_bf16(pa1, bv_[1][ht], o[ht],
                                                      0, 0, 0);
    }
  }

#pragma unroll
  for (int r = 0; r < 4; r++) {
    int row = wave * 16 + quad * 4 + r;
    size_t base = (((size_t)c * Bn + b) * NHEAD + h) * QPAD + row;
#pragma unroll
    for (int ht = 0; ht < 2; ht++)
      Ops[base * HDIM + ht * 16 + l15] = f2bf(o[ht][r]);
    if (l15 == 0) {
      Ml[base * 2]     = mrun[r];
      Ml[base * 2 + 1] = lrun[r];
    }
  }
}

// ---------------------------------------------------------------------------
// Kernel 4: chunk combine + out-projection + residual. CQ=4 queries/block,
// LDS-staged vectorized Ops/Ml loads.
// ---------------------------------------------------------------------------
__global__ __launch_bounds__(256) void combine_kernel(
    const short* __restrict__ Ops, const float* __restrict__ Ml,
    const float* __restrict__ query, const float* __restrict__ Wo,
    const float* __restrict__ bo, float* __restrict__ out, int Bn, int NQ) {
  int bpb = (NQ + CQ - 1) / CQ;
  int b  = blockIdx.x / bpb;
  int q0 = (blockIdx.x % bpb) * CQ;
  int tid = threadIdx.x;

  __shared__ __align__(16) short opsl[CQ][NCHUNK][DM];  // 16 KB
  __shared__ float mll[NCHUNK][NHEAD][CQ][2];           // 2 KB
  __shared__ __align__(16) float ctx[CQ * DM];          // 4 KB

  for (int t = tid; t < CQ * NCHUNK * (DM / 8); t += 256) {
    int q   = t / (NCHUNK * 32);
    int rem = t % (NCHUNK * 32);
    int c   = rem / 32;
    int v   = rem % 32;           // 8-elem chunk within 256 = h*32+hd0
    int h   = v >> 2;
    int hd0 = (v & 3) * 8;
    int qq = q0 + q;
    if (qq >= NQ) qq = NQ - 1;
    size_t base = (((size_t)c * Bn + b) * NHEAD + h) * QPAD + qq;
    *(bf16x8*)&opsl[q][c][v * 8] = *(const bf16x8*)&Ops[base * HDIM + hd0];
  }
  for (int t = tid; t < CQ * NCHUNK * NHEAD; t += 256) {
    int q   = t / (NCHUNK * NHEAD);
    int rem = t % (NCHUNK * NHEAD);
    int c   = rem / NHEAD;
    int h   = rem % NHEAD;
    int qq = q0 + q;
    if (qq >= NQ) qq = NQ - 1;
    size_t base = (((size_t)c * Bn + b) * NHEAD + h) * QPAD + qq;
    mll[c][h][q][0] = Ml[base * 2];
    mll[c][h][q][1] = Ml[base * 2 + 1];
  }
  __syncthreads();

  int d = tid, h = d >> 5;
#pragma unroll
  for (int qi = 0; qi < CQ; qi++) {
    float M = -1e30f;
#pragma unroll
    for (int c = 0; c < NCHUNK; c++) M = fmaxf(M, mll[c][h][qi][0]);
    float L = 0.f, acc = 0.f;
#pragma unroll
    for (int c = 0; c < NCHUNK; c++) {
      float w = __expf(mll[c][h][qi][0] - M);
      L += mll[c][h][qi][1] * w;
      acc += w * bf2f(opsl[qi][c][d]);
    }
    ctx[qi * DM + d] = (L > 0.f) ? acc / L : 0.f;
  }
  __syncthreads();

  const float* wrow = Wo + (size_t)d * DM;
  float acc[CQ];
  float bias = bo[d];
#pragma unroll
  for (int qi = 0; qi < CQ; qi++) acc[qi] = bias;
  for (int k = 0; k < DM; k += 4) {
    float4 w = *(const float4*)(wrow + k);
#pragma unroll
    for (int qi = 0; qi < CQ; qi++) {
      float4 x = *(const float4*)&ctx[qi * DM + k];
      acc[qi] += x.x * w.x + x.y * w.y + x.z * w.z + x.w * w.w;
    }
  }
#pragma unroll
  for (int qi = 0; qi < CQ; qi++) {
    int q = q0 + qi;
    if (q < NQ)
      out[((size_t)b * NQ + q) * DM + d] =
          acc[qi] + query[((size_t)b * NQ + q) * DM + d];
  }
}

// ---------------------------------------------------------------------------
extern "C" void kernel_launch(void* const* d_in, const int* in_sizes, int n_in,
                              void* d_out, int out_size, void* d_ws,
                              size_t ws_size, hipStream_t stream) {
  const float* src   = (const float*)d_in[0];
  const float* query = (const float*)d_in[1];
  const int*   offs  = (const int*)d_in[2];
  const float* Wq = (const float*)d_in[3];
  const float* bq = (const float*)d_in[4];
  const float* Wk = (const float*)d_in[5];
  const float* bk = (const float*)d_in[6];
  const float* Wv = (const float*)d_in[7];
  const float* bv = (const float*)d_in[8];
  const float* Wo = (const float*)d_in[9];
  const float* bo = (const float*)d_in[10];
  float* out = (float*)d_out;

  int T  = in_sizes[0] / DM;        // total tokens (65536)
  int Bn = in_sizes[2] - 1;         // batch size (16)
  int NQ = in_sizes[1] / (Bn * DM); // queries per sample (100)

  // Workspace layout (~77 MB):
  char* w = (char*)d_ws;
  size_t qsz = (size_t)Bn * NHEAD * QPAD * HDIM * 2;            // 0.92 MB
  size_t ksz = (size_t)T * DM * 2;                              // 33.5 MB
  size_t osz = (size_t)NCHUNK * Bn * NHEAD * QPAD * HDIM * 2;   // 7.3 MB (bf16)
  size_t msz = (size_t)NCHUNK * Bn * NHEAD * QPAD * 2 * 4;      // 0.92 MB
  short* Qw  = (short*)w;
  short* Kw  = (short*)(w + qsz);
  short* Vw  = (short*)(w + qsz + ksz);
  short* Ops = (short*)(w + qsz + 2 * ksz);
  float* Mlp = (float*)(w + qsz + 2 * ksz + osz);
  short* Wkv = (short*)(w + qsz + 2 * ksz + osz + msz);         // 0.26 MB

  int Mtiles = (T + BM - 1) / BM;
  int groups = (Mtiles + 7) / 8;
  int kvb = groups * 16;            // kv blocks (2048), first in the grid
  int nqb = Bn * (QPAD / QR);       // q_proj blocks (448), trailing filler

  wconv_kernel<<<(2 * DM * DM) / (256 * 8), 256, 0, stream>>>(Wk, Wv, Wkv);
  kvq_kernel<<<kvb + nqb, 256, 0, stream>>>(
      src, query, Wq, bq, Wkv, bk, bv, offs, Qw, Kw, Vw, T, Bn, NQ, Mtiles,
      kvb);
  attn_kernel<<<Bn * NHEAD * NCHUNK, 448, 0, stream>>>(Qw, Kw, Vw, offs, Ops,
                                                       Mlp, Bn);
  combine_kernel<<<Bn * ((NQ + CQ - 1) / CQ), 256, 0, stream>>>(
      Ops, Mlp, query, Wo, bo, out, Bn, NQ);
}

// Round 8
// 246.252 us; speedup vs baseline: 1.1025x; 1.0101x over previous
//
#include <hip/hip_runtime.h>
#include <hip/hip_bf16.h>
#include <math.h>

// Problem constants (fixed by the reference's weight shapes):
#define DM     256   // d_model
#define NHEAD  8
#define HDIM   32
#define QPAD   112   // padded query rows per (b,h): 7 waves x 16 rows
#define NCHUNK 8     // L-chunks per (b,h) for flash parallelism
#define BM     64    // kv_gemm M-tile (tokens)
#define BN     256   // kv_gemm N-tile (output cols): ntile 0 = K, 1 = V
#define BK     32    // kv_gemm K-step
#define ALD    264   // As row stride in shorts (256 + 8 pad)
#define QR     4     // q_proj rows per block
#define CQ     4     // combine queries per block

typedef __attribute__((ext_vector_type(8))) short bf16x8;  // 8 bf16 (4 VGPRs)
typedef __attribute__((ext_vector_type(4))) short bf16x4;  // 8B packed store
typedef __attribute__((ext_vector_type(4))) float f32x4;   // 4 fp32 acc

__device__ __forceinline__ short f2bf(float f) {
  union { float f; unsigned u; } x; x.f = f;
  unsigned u = (x.u + 0x7fffu + ((x.u >> 16) & 1u)) >> 16;
  return (short)u;
}
__device__ __forceinline__ float bf2f(short s) {
  union { unsigned u; float f; } x; x.u = ((unsigned)(unsigned short)s) << 16;
  return x.f;
}
__device__ __forceinline__ bf16x8 bzero8() {
  bf16x8 v;
#pragma unroll
  for (int j = 0; j < 8; j++) v[j] = (short)0;
  return v;
}
__device__ __forceinline__ bf16x8 cvt8(const float* p) {
  float4 x0 = *(const float4*)p, x1 = *(const float4*)(p + 4);
  bf16x8 v;
  v[0] = f2bf(x0.x); v[1] = f2bf(x0.y); v[2] = f2bf(x0.z); v[3] = f2bf(x0.w);
  v[4] = f2bf(x1.x); v[5] = f2bf(x1.y); v[6] = f2bf(x1.z); v[7] = f2bf(x1.w);
  return v;
}

// ---------------------------------------------------------------------------
// Kernel 0 (merged): wconv blocks [0, nwc) + q_proj blocks [nwc, nwc+448).
// Both are tiny and independent; merging saves one dispatch gap WITHOUT
// touching the kv dispatch (round-7 lesson: fusing q_proj into the kv grid
// serializes it as a +30 us tail — blocks dispatch in ID order).
// - wconv: Wkv[n][k] bf16; n<256 -> Wk row n, else Wv.
// - q_proj: q = (query @ Wq^T + bq) * scale -> Qw bf16, QR rows/block.
// ---------------------------------------------------------------------------
__global__ __launch_bounds__(256) void wq_kernel(
    const float* __restrict__ Wk, const float* __restrict__ Wv,
    short* __restrict__ Wkv, const float* __restrict__ query,
    const float* __restrict__ Wq, const float* __restrict__ bq,
    short* __restrict__ Qw, int Bn, int NQ, int nwc) {
  int tid = threadIdx.x;
  if (blockIdx.x < (unsigned)nwc) {
    // ---------------- wconv path ----------------
    int idx = blockIdx.x * 256 + tid;
    int e0 = idx * 8;
    const float* p = (e0 < DM * DM) ? (Wk + e0) : (Wv + (e0 - DM * DM));
    *(bf16x8*)(Wkv + e0) = cvt8(p);
    return;
  }
  // ---------------- q_proj path ----------------
  int qbid = blockIdx.x - nwc;
  int b  = qbid / (QPAD / QR);
  int r0 = (qbid % (QPAD / QR)) * QR;
  __shared__ __align__(16) float ql[QR * DM];
  for (int i = tid; i < QR * DM; i += 256) {
    int r = r0 + (i >> 8);
    ql[i] = (r < NQ) ? query[((size_t)b * NQ + r) * DM + (i & 255)] : 0.f;
  }
  __syncthreads();
  int d = tid;
  float bias = bq[d];
  float acc[QR];
#pragma unroll
  for (int qi = 0; qi < QR; qi++) acc[qi] = bias;
  const float* wrow = Wq + (size_t)d * DM;
  for (int k = 0; k < DM; k += 4) {
    float4 w = *(const float4*)(wrow + k);
#pragma unroll
    for (int qi = 0; qi < QR; qi++) {
      float4 x = *(const float4*)&ql[qi * DM + k];
      acc[qi] += x.x * w.x + x.y * w.y + x.z * w.z + x.w * w.w;
    }
  }
  const float scale = 0.17677669529663687f;  // 1/sqrt(32)
  int h = d >> 5, hd = d & 31;
#pragma unroll
  for (int qi = 0; qi < QR; qi++) {
    int r = r0 + qi;
    float v = (r < NQ) ? acc[qi] * scale : 0.f;
    Qw[(((size_t)b * NHEAD + h) * QPAD + r) * HDIM + hd] = f2bf(v);
  }
}

// ---------------------------------------------------------------------------
// Kernel 2: KV projection GEMM, 64x256 tile, 4 waves (1x4 over N).
// EXACT round-4/5 measured-best config (70-72 us): stage ALL of A (64x256
// bf16 = 33.8 KB) into LDS once, then a barrier-free K-loop; B fragments
// read from the L2-resident bf16 Wkv straight into MFMA layout.
// K/V-paired grid: the K and V blocks of one mtile share bid%8 (same XCD)
// and are 8 IDs apart -> src re-read is an L2 hit (FETCH ~34 MB).
// K tiles use SWAPPED mfma operands (C^T); V tiles normal orientation.
// ---------------------------------------------------------------------------
__global__ __launch_bounds__(256) void kv_gemm_kernel(
    const float* __restrict__ src, const short* __restrict__ Wkv,
    const float* __restrict__ bk, const float* __restrict__ bv,
    const int* __restrict__ offs, short* __restrict__ Kw,
    short* __restrict__ Vw, int T, int Bn, int Mtiles) {
  int bid = blockIdx.x;
  int mtile = (bid >> 4) * 8 + (bid & 7);
  int ntile = (bid >> 3) & 1;
  if (mtile >= Mtiles) return;
  int t0 = mtile * BM;
  int n0 = ntile * BN;           // 0 => K cols, 256 => V cols
  bool isK = (ntile == 0);
  const float* bias = isK ? bk : bv;

  int tid = threadIdx.x;
  int wave = tid >> 6, lane = tid & 63;
  int l15 = lane & 15, quad = lane >> 4;

  __shared__ __align__(16) short As[BM * ALD];  // full-K A tile, bf16

  f32x4 acc[4][4];
#pragma unroll
  for (int i = 0; i < 4; i++)
#pragma unroll
    for (int j = 0; j < 4; j++) acc[i][j] = (f32x4){0.f, 0.f, 0.f, 0.f};

  // ---- prologue: stage all of A (fp32 -> bf16), one barrier total ----
  {
    int arow = tid >> 2, ac4 = tid & 3;
    int atok = t0 + arow;
    if (atok >= T) atok = T - 1;
    const float* arp = src + (size_t)atok * DM;
#pragma unroll
    for (int r = 0; r < 4; r++) {
      int c0 = r * 64 + ac4 * 16;
      const float* p = arp + c0;
      bf16x8 v0 = cvt8(p);
      bf16x8 v1 = cvt8(p + 8);
      *(bf16x8*)&As[arow * ALD + c0]     = v0;
      *(bf16x8*)&As[arow * ALD + c0 + 8] = v1;
    }
  }
  __syncthreads();

  // ---- barrier-free K-loop: B from bf16 Wkv (L2), A from LDS ----
  const short* bptr = Wkv + (size_t)(n0 + wave * 64 + l15) * DM + quad * 8;
#pragma unroll
  for (int kk = 0; kk < DM; kk += BK) {
    bf16x8 bf_[4];
#pragma unroll
    for (int nt = 0; nt < 4; nt++)
      bf_[nt] = *(const bf16x8*)(bptr + (size_t)nt * 16 * DM + kk);
    bf16x8 af[4];
#pragma unroll
    for (int mt = 0; mt < 4; mt++)
      af[mt] = *(const bf16x8*)&As[(mt * 16 + l15) * ALD + kk + quad * 8];
    if (isK) {
#pragma unroll
      for (int mt = 0; mt < 4; mt++)
#pragma unroll
        for (int nt = 0; nt < 4; nt++)
          acc[mt][nt] = __builtin_amdgcn_mfma_f32_16x16x32_bf16(
              bf_[nt], af[mt], acc[mt][nt], 0, 0, 0);  // C^T
    } else {
#pragma unroll
      for (int mt = 0; mt < 4; mt++)
#pragma unroll
        for (int nt = 0; nt < 4; nt++)
          acc[mt][nt] = __builtin_amdgcn_mfma_f32_16x16x32_bf16(
              af[mt], bf_[nt], acc[mt][nt], 0, 0, 0);
    }
  }

  if (isK) {
    // C^T: lane l15 = token (within 16), reg r = hd offset quad*4+r.
    float bk4[4][4];
    int hK[4], hdK[4];
#pragma unroll
    for (int nt = 0; nt < 4; nt++) {
      int nbq = wave * 64 + nt * 16 + quad * 4;
      float4 b4 = *(const float4*)(bias + nbq);
      bk4[nt][0] = b4.x; bk4[nt][1] = b4.y; bk4[nt][2] = b4.z; bk4[nt][3] = b4.w;
      hK[nt] = nbq >> 5;
      hdK[nt] = nbq & 31;
    }
    int bcur = 0;
#pragma unroll
    for (int mt = 0; mt < 4; mt++) {
      int tok = t0 + mt * 16 + l15;
      if (tok >= T) continue;
      while (bcur + 1 < Bn && offs[bcur + 1] <= tok) bcur++;
      int off = offs[bcur], len = offs[bcur + 1] - off;
      int l = tok - off;
      size_t bb = (size_t)off * DM;
#pragma unroll
      for (int nt = 0; nt < 4; nt++) {
        bf16x4 p;
#pragma unroll
        for (int r = 0; r < 4; r++) p[r] = f2bf(acc[mt][nt][r] + bk4[nt][r]);
        *(bf16x4*)&Kw[bb + (size_t)hK[nt] * len * HDIM + (size_t)l * HDIM +
                      hdK[nt]] = p;
      }
    }
  } else {
    // Normal C: lane l15 = hd (within 16), reg r = token offset quad*4+r.
    float bV[4];
    int hV[4], hdV[4];
#pragma unroll
    for (int nt = 0; nt < 4; nt++) {
      int nb = wave * 64 + nt * 16 + l15;
      bV[nt] = bias[nb];
      hV[nt] = nb >> 5;
      hdV[nt] = nb & 31;
    }
    int bcur = 0;
#pragma unroll
    for (int mt = 0; mt < 4; mt++) {
      int tb = t0 + mt * 16 + quad * 4;
      if (tb >= T) continue;
      while (bcur + 1 < Bn && offs[bcur + 1] <= tb) bcur++;
      int off = offs[bcur], len = offs[bcur + 1] - off;
      size_t bb = (size_t)off * DM;
      bool span = (tb + 3 < offs[bcur + 1]) && (tb + 3 < T);
      if (span) {
        int l = tb - off;
#pragma unroll
        for (int nt = 0; nt < 4; nt++) {
          size_t idx =
              bb + (size_t)hV[nt] * len * HDIM + (size_t)hdV[nt] * len + l;
          bf16x4 p;
#pragma unroll
          for (int r = 0; r < 4; r++) p[r] = f2bf(acc[mt][nt][r] + bV[nt]);
          if ((idx & 3) == 0) {
            *(bf16x4*)&Vw[idx] = p;
          } else {
#pragma unroll
            for (int r = 0; r < 4; r++) Vw[idx + r] = p[r];
          }
        }
      } else {
        int bc2 = bcur;
#pragma unroll
        for (int r = 0; r < 4; r++) {
          int tok = tb + r;
          if (tok >= T) continue;
          while (bc2 + 1 < Bn && offs[bc2 + 1] <= tok) bc2++;
          int off2 = offs[bc2], len2 = offs[bc2 + 1] - off2;
          int l = tok - off2;
          size_t bb2 = (size_t)off2 * DM;
#pragma unroll
          for (int nt = 0; nt < 4; nt++)
            Vw[bb2 + (size_t)hV[nt] * len2 * HDIM + (size_t)hdV[nt] * len2 +
               l] = f2bf(acc[mt][nt][r] + bV[nt]);
        }
      }
    }
  }
}

// ---------------------------------------------------------------------------
// Kernel 3: flash attention per (b, h, chunk). 7 waves x 16 query rows.
// 64-key iterations (4 QK tiles/step): shfl cascade amortized over 64 keys,
// serial m-chain 9 iterations instead of 17.
// Writes unnormalized O (QPAD x 32, bf16) + per-row (m, l) fp32.
// ---------------------------------------------------------------------------
__global__ __launch_bounds__(448) void attn_kernel(
    const short* __restrict__ Qw, const short* __restrict__ Kw,
    const short* __restrict__ Vw, const int* __restrict__ offs,
    short* __restrict__ Ops, float* __restrict__ Ml, int Bn) {
  int c  = blockIdx.x % NCHUNK;
  int bh = blockIdx.x / NCHUNK;
  int h = bh % NHEAD, b = bh / NHEAD;
  int wave = threadIdx.x >> 6, lane = threadIdx.x & 63;
  int l15 = lane & 15, quad = lane >> 4;

  int off = offs[b], len = offs[b + 1] - off;
  int cl = ((len + NCHUNK * 32 - 1) / (NCHUNK * 32)) * 32;
  int kstart = c * cl;
  int kend   = min(kstart + cl, len);

  const short* Kh = Kw + (size_t)off * DM + (size_t)h * len * HDIM;
  const short* Vh = Vw + (size_t)off * DM + (size_t)h * len * HDIM;

  int row16 = wave * 16 + l15;
  bf16x8 aq = *(const bf16x8*)(
      Qw + (((size_t)b * NHEAD + h) * QPAD + row16) * HDIM + quad * 8);

  f32x4 o[2];
#pragma unroll
  for (int j = 0; j < 2; j++) o[j] = (f32x4){0.f, 0.f, 0.f, 0.f};
  float mrun[4], lrun[4];
#pragma unroll
  for (int r = 0; r < 4; r++) { mrun[r] = -1e30f; lrun[r] = 0.f; }

  __shared__ __align__(16) short plds[7][16][72];  // wave-private P transpose

  for (int kb = kstart; kb < kend; kb += 64) {
    bool valid[4];
    bf16x8 bk_[4];
#pragma unroll
    for (int nt = 0; nt < 4; nt++) {
      int key = kb + nt * 16 + l15;
      valid[nt] = key < kend;
      bk_[nt] = valid[nt]
                    ? *(const bf16x8*)(Kh + (size_t)key * HDIM + quad * 8)
                    : bzero8();
    }
    f32x4 zero = {0.f, 0.f, 0.f, 0.f};
    f32x4 s[4];
#pragma unroll
    for (int nt = 0; nt < 4; nt++)
      s[nt] = __builtin_amdgcn_mfma_f32_16x16x32_bf16(aq, bk_[nt], zero, 0, 0, 0);
#pragma unroll
    for (int r = 0; r < 4; r++) {
      float v0 = valid[0] ? s[0][r] : -1e30f;
      float v1 = valid[1] ? s[1][r] : -1e30f;
      float v2 = valid[2] ? s[2][r] : -1e30f;
      float v3 = valid[3] ? s[3][r] : -1e30f;
      float t = fmaxf(fmaxf(v0, v1), fmaxf(v2, v3));
      t = fmaxf(t, __shfl_xor(t, 1, 16));
      t = fmaxf(t, __shfl_xor(t, 2, 16));
      t = fmaxf(t, __shfl_xor(t, 4, 16));
      t = fmaxf(t, __shfl_xor(t, 8, 16));
      float mn = fmaxf(mrun[r], t);
      float al = __expf(mrun[r] - mn);
      float p0 = valid[0] ? __expf(v0 - mn) : 0.f;
      float p1 = valid[1] ? __expf(v1 - mn) : 0.f;
      float p2 = valid[2] ? __expf(v2 - mn) : 0.f;
      float p3 = valid[3] ? __expf(v3 - mn) : 0.f;
      float rs = (p0 + p1) + (p2 + p3);
      rs += __shfl_xor(rs, 1, 16);
      rs += __shfl_xor(rs, 2, 16);
      rs += __shfl_xor(rs, 4, 16);
      rs += __shfl_xor(rs, 8, 16);
      lrun[r] = al * lrun[r] + rs;
      mrun[r] = mn;
      o[0][r] *= al;
      o[1][r] *= al;
      plds[wave][quad * 4 + r][l15]      = f2bf(p0);
      plds[wave][quad * 4 + r][16 + l15] = f2bf(p1);
      plds[wave][quad * 4 + r][32 + l15] = f2bf(p2);
      plds[wave][quad * 4 + r][48 + l15] = f2bf(p3);
    }
    bf16x8 pa0 = *(const bf16x8*)&plds[wave][l15][quad * 8];
    bf16x8 pa1 = *(const bf16x8*)&plds[wave][l15][32 + quad * 8];
    bf16x8 bv_[2][2];
#pragma unroll
    for (int half = 0; half < 2; half++) {
#pragma unroll
      for (int ht = 0; ht < 2; ht++) {
        int hd = ht * 16 + l15;
        int k0 = kb + half * 32 + quad * 8;
        const short* p = Vh + (size_t)hd * len + k0;
        if (k0 + 7 < len) {
          bv_[half][ht] = *(const bf16x8*)p;
        } else {
          bf16x8 v;
#pragma unroll
          for (int j = 0; j < 8; j++) v[j] = (k0 + j < len) ? p[j] : (short)0;
          bv_[half][ht] = v;
        }
      }
    }
#pragma unroll
    for (int ht = 0; ht < 2; ht++) {
      o[ht] = __builtin_amdgcn_mfma_f32_16x16x32_bf16(pa0, bv_[0][ht], o[ht],
                                                      0, 0, 0);
      o[ht] = __builtin_amdgcn_mfma_f32_16x16x32_bf16(pa1, bv_[1][ht], o[ht],
                                                      0, 0, 0);
    }
  }

#pragma unroll
  for (int r = 0; r < 4; r++) {
    int row = wave * 16 + quad * 4 + r;
    size_t base = (((size_t)c * Bn + b) * NHEAD + h) * QPAD + row;
#pragma unroll
    for (int ht = 0; ht < 2; ht++)
      Ops[base * HDIM + ht * 16 + l15] = f2bf(o[ht][r]);
    if (l15 == 0) {
      Ml[base * 2]     = mrun[r];
      Ml[base * 2 + 1] = lrun[r];
    }
  }
}

// ---------------------------------------------------------------------------
// Kernel 4: chunk combine + out-projection + residual. CQ=4 queries/block,
// LDS-staged vectorized Ops/Ml loads.
// ---------------------------------------------------------------------------
__global__ __launch_bounds__(256) void combine_kernel(
    const short* __restrict__ Ops, const float* __restrict__ Ml,
    const float* __restrict__ query, const float* __restrict__ Wo,
    const float* __restrict__ bo, float* __restrict__ out, int Bn, int NQ) {
  int bpb = (NQ + CQ - 1) / CQ;
  int b  = blockIdx.x / bpb;
  int q0 = (blockIdx.x % bpb) * CQ;
  int tid = threadIdx.x;

  __shared__ __align__(16) short opsl[CQ][NCHUNK][DM];  // 16 KB
  __shared__ float mll[NCHUNK][NHEAD][CQ][2];           // 2 KB
  __shared__ __align__(16) float ctx[CQ * DM];          // 4 KB

  for (int t = tid; t < CQ * NCHUNK * (DM / 8); t += 256) {
    int q   = t / (NCHUNK * 32);
    int rem = t % (NCHUNK * 32);
    int c   = rem / 32;
    int v   = rem % 32;           // 8-elem chunk within 256 = h*32+hd0
    int h   = v >> 2;
    int hd0 = (v & 3) * 8;
    int qq = q0 + q;
    if (qq >= NQ) qq = NQ - 1;
    size_t base = (((size_t)c * Bn + b) * NHEAD + h) * QPAD + qq;
    *(bf16x8*)&opsl[q][c][v * 8] = *(const bf16x8*)&Ops[base * HDIM + hd0];
  }
  for (int t = tid; t < CQ * NCHUNK * NHEAD; t += 256) {
    int q   = t / (NCHUNK * NHEAD);
    int rem = t % (NCHUNK * NHEAD);
    int c   = rem / NHEAD;
    int h   = rem % NHEAD;
    int qq = q0 + q;
    if (qq >= NQ) qq = NQ - 1;
    size_t base = (((size_t)c * Bn + b) * NHEAD + h) * QPAD + qq;
    mll[c][h][q][0] = Ml[base * 2];
    mll[c][h][q][1] = Ml[base * 2 + 1];
  }
  __syncthreads();

  int d = tid, h = d >> 5;
#pragma unroll
  for (int qi = 0; qi < CQ; qi++) {
    float M = -1e30f;
#pragma unroll
    for (int c = 0; c < NCHUNK; c++) M = fmaxf(M, mll[c][h][qi][0]);
    float L = 0.f, acc = 0.f;
#pragma unroll
    for (int c = 0; c < NCHUNK; c++) {
      float w = __expf(mll[c][h][qi][0] - M);
      L += mll[c][h][qi][1] * w;
      acc += w * bf2f(opsl[qi][c][d]);
    }
    ctx[qi * DM + d] = (L > 0.f) ? acc / L : 0.f;
  }
  __syncthreads();

  const float* wrow = Wo + (size_t)d * DM;
  float acc[CQ];
  float bias = bo[d];
#pragma unroll
  for (int qi = 0; qi < CQ; qi++) acc[qi] = bias;
  for (int k = 0; k < DM; k += 4) {
    float4 w = *(const float4*)(wrow + k);
#pragma unroll
    for (int qi = 0; qi < CQ; qi++) {
      float4 x = *(const float4*)&ctx[qi * DM + k];
      acc[qi] += x.x * w.x + x.y * w.y + x.z * w.z + x.w * w.w;
    }
  }
#pragma unroll
  for (int qi = 0; qi < CQ; qi++) {
    int q = q0 + qi;
    if (q < NQ)
      out[((size_t)b * NQ + q) * DM + d] =
          acc[qi] + query[((size_t)b * NQ + q) * DM + d];
  }
}

// ---------------------------------------------------------------------------
extern "C" void kernel_launch(void* const* d_in, const int* in_sizes, int n_in,
                              void* d_out, int out_size, void* d_ws,
                              size_t ws_size, hipStream_t stream) {
  const float* src   = (const float*)d_in[0];
  const float* query = (const float*)d_in[1];
  const int*   offs  = (const int*)d_in[2];
  const float* Wq = (const float*)d_in[3];
  const float* bq = (const float*)d_in[4];
  const float* Wk = (const float*)d_in[5];
  const float* bk = (const float*)d_in[6];
  const float* Wv = (const float*)d_in[7];
  const float* bv = (const float*)d_in[8];
  const float* Wo = (const float*)d_in[9];
  const float* bo = (const float*)d_in[10];
  float* out = (float*)d_out;

  int T  = in_sizes[0] / DM;        // total tokens (65536)
  int Bn = in_sizes[2] - 1;         // batch size (16)
  int NQ = in_sizes[1] / (Bn * DM); // queries per sample (100)

  // Workspace layout (~77 MB):
  char* w = (char*)d_ws;
  size_t qsz = (size_t)Bn * NHEAD * QPAD * HDIM * 2;            // 0.92 MB
  size_t ksz = (size_t)T * DM * 2;                              // 33.5 MB
  size_t osz = (size_t)NCHUNK * Bn * NHEAD * QPAD * HDIM * 2;   // 7.3 MB (bf16)
  size_t msz = (size_t)NCHUNK * Bn * NHEAD * QPAD * 2 * 4;      // 0.92 MB
  short* Qw  = (short*)w;
  short* Kw  = (short*)(w + qsz);
  short* Vw  = (short*)(w + qsz + ksz);
  short* Ops = (short*)(w + qsz + 2 * ksz);
  float* Mlp = (float*)(w + qsz + 2 * ksz + osz);
  short* Wkv = (short*)(w + qsz + 2 * ksz + osz + msz);         // 0.26 MB

  int Mtiles = (T + BM - 1) / BM;
  int groups = (Mtiles + 7) / 8;
  int nwc = (2 * DM * DM) / (256 * 8);  // wconv blocks (64)
  int nqb = Bn * (QPAD / QR);           // q_proj blocks (448)

  wq_kernel<<<nwc + nqb, 256, 0, stream>>>(Wk, Wv, Wkv, query, Wq, bq, Qw, Bn,
                                           NQ, nwc);
  kv_gemm_kernel<<<groups * 16, 256, 0, stream>>>(
      src, Wkv, bk, bv, offs, Kw, Vw, T, Bn, Mtiles);
  attn_kernel<<<Bn * NHEAD * NCHUNK, 448, 0, stream>>>(Qw, Kw, Vw, offs, Ops,
                                                       Mlp, Bn);
  combine_kernel<<<Bn * ((NQ + CQ - 1) / CQ), 256, 0, stream>>>(
      Ops, Mlp, query, Wo, bo, out, Bn, NQ);
}